// Round 1
// baseline (71434.106 us; speedup 1.0000x reference)
//
#include <hip/hip_runtime.h>
#include <math.h>

#define B64   64
#define TT    512
#define U400  400
#define G1600 1600

// x [64][512][3] -> xT [512][3][64]
__global__ void xpose_x_k(const float* __restrict__ x, float* __restrict__ xT) {
  int idx = blockIdx.x * 256 + threadIdx.x;
  if (idx < B64 * TT * 3) {
    int d = idx % 3;
    int t = (idx / 3) % TT;
    int b = idx / (3 * TT);
    xT[(t * 3 + d) * B64 + b] = x[idx];
  }
}

// generic tiled transpose: in R x C -> out C x R
__global__ void transpose_k(const float* __restrict__ in, float* __restrict__ out,
                            int R, int C) {
  __shared__ float tile[32][33];
  int bx = blockIdx.x * 32, by = blockIdx.y * 32;
  int tx = threadIdx.x, ty = threadIdx.y; // block (32,8)
  #pragma unroll
  for (int i = ty; i < 32; i += 8) {
    int r = by + i, c = bx + tx;
    if (r < R && c < C) tile[i][tx] = in[(size_t)r * C + c];
  }
  __syncthreads();
  #pragma unroll
  for (int i = ty; i < 32; i += 8) {
    int r = bx + i, c = by + tx;
    if (r < C && c < R) out[(size_t)r * R + c] = tile[tx][i];
  }
}

// One LSTM timestep. Block = one unit u (4 waves = 4 gates, lane = batch).
// xin: [T][D][64]   (layer0: transposed x, D=3; layers1/2: previous layer h, D=400)
// Wx : D==3 -> raw Wx0 [3][1600]; else WxT [1600][400]
// WhT: [1600][400]
// hbuf: [512][400][64] — reads slot t-1 (own layer), writes slot t
__launch_bounds__(256)
__global__ void lstm_step_k(
    const float* __restrict__ xin,
    const float* __restrict__ Wx,
    const float* __restrict__ WhT,
    const float* __restrict__ bias,
    const float* __restrict__ pi, const float* __restrict__ pf,
    const float* __restrict__ po,
    float* __restrict__ cT,      // [400][64]
    float* __restrict__ hbuf,
    int t, int D)
{
  const int u    = blockIdx.x;
  const int w    = threadIdx.x >> 6;   // gate 0..3 (i,f,g,o)
  const int lane = threadIdx.x & 63;   // batch
  const int col  = w * U400 + u;       // column in [0,1600)

  float acc = bias[col];

  const float* xrow = xin + (size_t)t * D * B64 + lane;
  if (D == 3) {
    acc += xrow[0 * B64] * Wx[0 * G1600 + col];
    acc += xrow[1 * B64] * Wx[1 * G1600 + col];
    acc += xrow[2 * B64] * Wx[2 * G1600 + col];
  } else {
    const float* wr = Wx + (size_t)col * U400;
    #pragma unroll 4
    for (int d = 0; d < U400; ++d) acc += xrow[(size_t)d * B64] * wr[d];
  }

  if (t > 0) {
    const float* hrow = hbuf + (size_t)(t - 1) * U400 * B64 + lane;
    const float* wr = WhT + (size_t)col * U400;
    #pragma unroll 4
    for (int k = 0; k < U400; ++k) acc += hrow[(size_t)k * B64] * wr[k];
  }

  __shared__ float zs[4][B64];
  zs[w][lane] = acc;
  __syncthreads();

  if (threadIdx.x < B64) {
    const int b = threadIdx.x;
    float cp = (t == 0) ? 0.f : cT[u * B64 + b];
    float zi = zs[0][b] + pi[u] * cp;
    float zf = zs[1][b] + pf[u] * cp;
    float zg = zs[2][b];
    float ig = 1.f / (1.f + expf(-zi));
    float fg = 1.f / (1.f + expf(-zf));
    float gg = tanhf(zg);
    float cn = fg * cp + ig * gg;
    float zo = zs[3][b] + po[u] * cn;
    float og = 1.f / (1.f + expf(-zo));
    float h  = og * tanhf(cn);
    cT[u * B64 + b] = cn;
    hbuf[((size_t)t * U400 + u) * B64 + b] = h;
  }
}

// out[b][t][f] = bd[f] + sum_u h2[t][u][b] * Wd[u][f]
__launch_bounds__(256)
__global__ void dense_k(const float* __restrict__ h2, const float* __restrict__ Wd,
                        const float* __restrict__ bd, float* __restrict__ out) {
  int wid  = blockIdx.x * 4 + (threadIdx.x >> 6);
  int lane = threadIdx.x & 63;
  int t = wid / 3, f = wid - t * 3;
  if (t >= TT) return;
  float acc = bd[f];
  const float* hrow = h2 + (size_t)t * U400 * B64 + lane;
  #pragma unroll 4
  for (int u = 0; u < U400; ++u) acc += hrow[(size_t)u * B64] * Wd[u * 3 + f];
  out[((size_t)lane * TT + t) * 3 + f] = acc;
}

extern "C" void kernel_launch(void* const* d_in, const int* in_sizes, int n_in,
                              void* d_out, int out_size, void* d_ws, size_t ws_size,
                              hipStream_t stream) {
  const float* x   = (const float*)d_in[0];
  const float* Wx0 = (const float*)d_in[1];
  const float* Wh0 = (const float*)d_in[2];
  const float* pi0 = (const float*)d_in[3];
  const float* pf0 = (const float*)d_in[4];
  const float* po0 = (const float*)d_in[5];
  const float* b0  = (const float*)d_in[6];
  const float* Wx1 = (const float*)d_in[7];
  const float* Wh1 = (const float*)d_in[8];
  const float* pi1 = (const float*)d_in[9];
  const float* pf1 = (const float*)d_in[10];
  const float* po1 = (const float*)d_in[11];
  const float* b1  = (const float*)d_in[12];
  const float* Wx2 = (const float*)d_in[13];
  const float* Wh2 = (const float*)d_in[14];
  const float* pi2 = (const float*)d_in[15];
  const float* pf2 = (const float*)d_in[16];
  const float* po2 = (const float*)d_in[17];
  const float* b2  = (const float*)d_in[18];
  const float* Wd  = (const float*)d_in[19];
  const float* bd  = (const float*)d_in[20];

  float* ws   = (float*)d_ws;
  float* xT0  = ws;                  // 98304
  float* WhT0 = xT0  + 98304;        // 640000 each
  float* WhT1 = WhT0 + 640000;
  float* WhT2 = WhT1 + 640000;
  float* WxT1 = WhT2 + 640000;
  float* WxT2 = WxT1 + 640000;
  float* cT   = WxT2 + 640000;       // 25600
  float* hA   = cT   + 25600;        // 13107200 each
  float* hB   = hA   + 13107200;

  hipLaunchKernelGGL(xpose_x_k, dim3(384), dim3(256), 0, stream, x, xT0);

  dim3 tb(32, 8);
  dim3 tg((G1600 + 31) / 32, (U400 + 31) / 32);
  hipLaunchKernelGGL(transpose_k, tg, tb, 0, stream, Wh0, WhT0, U400, G1600);
  hipLaunchKernelGGL(transpose_k, tg, tb, 0, stream, Wh1, WhT1, U400, G1600);
  hipLaunchKernelGGL(transpose_k, tg, tb, 0, stream, Wh2, WhT2, U400, G1600);
  hipLaunchKernelGGL(transpose_k, tg, tb, 0, stream, Wx1, WxT1, U400, G1600);
  hipLaunchKernelGGL(transpose_k, tg, tb, 0, stream, Wx2, WxT2, U400, G1600);

  // layer 0: xin = xT0 (D=3), state hA
  for (int t = 0; t < TT; ++t)
    hipLaunchKernelGGL(lstm_step_k, dim3(U400), dim3(256), 0, stream,
                       xT0, Wx0, WhT0, b0, pi0, pf0, po0, cT, hA, t, 3);
  // layer 1: xin = hA, state hB
  for (int t = 0; t < TT; ++t)
    hipLaunchKernelGGL(lstm_step_k, dim3(U400), dim3(256), 0, stream,
                       hA, WxT1, WhT1, b1, pi1, pf1, po1, cT, hB, t, U400);
  // layer 2: xin = hB, state hA (overwrites layer-0 output, no longer needed)
  for (int t = 0; t < TT; ++t)
    hipLaunchKernelGGL(lstm_step_k, dim3(U400), dim3(256), 0, stream,
                       hB, WxT2, WhT2, b2, pi2, pf2, po2, cT, hA, t, U400);

  hipLaunchKernelGGL(dense_k, dim3(384), dim3(256), 0, stream, hA, Wd, bd,
                     (float*)d_out);
}

// Round 2
// 40768.451 us; speedup vs baseline: 1.7522x; 1.7522x over previous
//
#include <hip/hip_runtime.h>
#include <math.h>

#define B64   64
#define TT    512
#define U400  400
#define G1600 1600

// x [64][512][3] -> xT [512][3][64]
__global__ void xpose_x_k(const float* __restrict__ x, float* __restrict__ xT) {
  int idx = blockIdx.x * 256 + threadIdx.x;
  if (idx < B64 * TT * 3) {
    int d = idx % 3;
    int t = (idx / 3) % TT;
    int b = idx / (3 * TT);
    xT[(t * 3 + d) * B64 + b] = x[idx];
  }
}

// generic tiled transpose: in R x C -> out C x R
__global__ void transpose_k(const float* __restrict__ in, float* __restrict__ out,
                            int R, int C) {
  __shared__ float tile[32][33];
  int bx = blockIdx.x * 32, by = blockIdx.y * 32;
  int tx = threadIdx.x, ty = threadIdx.y; // block (32,8)
  #pragma unroll
  for (int i = ty; i < 32; i += 8) {
    int r = by + i, c = bx + tx;
    if (r < R && c < C) tile[i][tx] = in[(size_t)r * C + c];
  }
  __syncthreads();
  #pragma unroll
  for (int i = ty; i < 32; i += 8) {
    int r = bx + i, c = by + tx;
    if (r < C && c < R) out[(size_t)r * R + c] = tile[tx][i];
  }
}

// One LSTM timestep.
// Block = one unit u. 4 waves = 4 K-quarters. lane = batch b.
// Each thread accumulates ALL FOUR gate columns of unit u over its K-slice
// (1 LDS read feeds 4 FMAs). Wave-private LDS chunks, register double-buffer
// for global->LDS staging; no intra-step __syncthreads until the reduce.
//
// Layers 1/2 (L0=0): combined K=800: k in [0,400) = xslab (prev layer h at t),
//                    k in [400,800) = own h at t-1. kq 0,1 -> x part; 2,3 -> h part.
// Layer 0  (L0=1): waves split own-h K=400 in quarters of 100; wave 0 also adds
//                  the 3-feature x contribution with scalar weights.
template <int L0>
__launch_bounds__(256)
__global__ void lstm_step_k(const float* __restrict__ xslab,  // L0: xT0+t*192 ; else prevbuf+t*400*64
                            float* __restrict__ hbuf,          // own layer [512][400][64]
                            const float* __restrict__ Wx0,     // L0 only: raw [3][1600]
                            const float* __restrict__ WxT,     // !L0: [1600][400]
                            const float* __restrict__ WhT,     // [1600][400]
                            const float* __restrict__ bias,
                            const float* __restrict__ pi,
                            const float* __restrict__ pf,
                            const float* __restrict__ po,
                            float* __restrict__ cT,            // [400][64]
                            int t)
{
  const int u    = blockIdx.x;
  const int lane = threadIdx.x & 63;
  const int kq   = __builtin_amdgcn_readfirstlane(threadIdx.x >> 6);

  constexpr int CHk = L0 ? 20 : 40;   // k per chunk
  constexpr int NF4 = CHk / 4;        // float4 loads per lane per chunk

  __shared__ float lds[4][40][B64];   // 40 KB, wave-private [kq] regions
  __shared__ float zs[4][4][B64];     // [gate][kq][b] partials

  float acc0 = 0.f, acc1 = 0.f, acc2 = 0.f, acc3 = 0.f;

  // ---- select this wave's slab + weight base ----
  const float* slab = nullptr;
  int k0 = 0;
  const float* wbase;
  if (L0) {
    wbase = WhT;
    k0 = kq * 100;
    if (t > 0) slab = hbuf + (size_t)(t - 1) * U400 * B64 + (size_t)k0 * B64;
  } else {
    if (kq < 2) {
      wbase = WxT; k0 = kq * 200;
      slab = xslab + (size_t)k0 * B64;
    } else {
      wbase = WhT; k0 = (kq - 2) * 200;
      if (t > 0) slab = hbuf + (size_t)(t - 1) * U400 * B64 + (size_t)k0 * B64;
    }
  }
  const float* w0 = wbase + (size_t)(0 * U400 + u) * U400;
  const float* w1 = wbase + (size_t)(1 * U400 + u) * U400;
  const float* w2 = wbase + (size_t)(2 * U400 + u) * U400;
  const float* w3 = wbase + (size_t)(3 * U400 + u) * U400;

  if (slab) {
    const float4* src = (const float4*)slab;
    float4* dst = (float4*)&lds[kq][0][0];
    float4 r[NF4];
    #pragma unroll
    for (int i = 0; i < NF4; ++i) r[i] = src[i * 64 + lane];
    for (int c = 0; c < 5; ++c) {
      // commit chunk c to LDS
      #pragma unroll
      for (int i = 0; i < NF4; ++i) dst[i * 64 + lane] = r[i];
      // prefetch chunk c+1 into registers (hides L2 latency under compute)
      if (c < 4) {
        const float4* s2 = src + (size_t)(c + 1) * CHk * 16;
        #pragma unroll
        for (int i = 0; i < NF4; ++i) r[i] = s2[i * 64 + lane];
      }
      // consume chunk c (wave-private: no barrier needed)
      #pragma unroll
      for (int kk = 0; kk < CHk; ++kk) {
        float a = lds[kq][kk][lane];
        int k = k0 + c * CHk + kk;
        acc0 += a * w0[k];
        acc1 += a * w1[k];
        acc2 += a * w2[k];
        acc3 += a * w3[k];
      }
    }
  }

  if (L0 && kq == 0) {
    float xv0 = xslab[0 * B64 + lane];
    float xv1 = xslab[1 * B64 + lane];
    float xv2 = xslab[2 * B64 + lane];
    acc0 += xv0 * Wx0[0 * G1600 + 0 * U400 + u] + xv1 * Wx0[1 * G1600 + 0 * U400 + u] + xv2 * Wx0[2 * G1600 + 0 * U400 + u];
    acc1 += xv0 * Wx0[0 * G1600 + 1 * U400 + u] + xv1 * Wx0[1 * G1600 + 1 * U400 + u] + xv2 * Wx0[2 * G1600 + 1 * U400 + u];
    acc2 += xv0 * Wx0[0 * G1600 + 2 * U400 + u] + xv1 * Wx0[1 * G1600 + 2 * U400 + u] + xv2 * Wx0[2 * G1600 + 2 * U400 + u];
    acc3 += xv0 * Wx0[0 * G1600 + 3 * U400 + u] + xv1 * Wx0[1 * G1600 + 3 * U400 + u] + xv2 * Wx0[2 * G1600 + 3 * U400 + u];
  }

  zs[0][kq][lane] = acc0;
  zs[1][kq][lane] = acc1;
  zs[2][kq][lane] = acc2;
  zs[3][kq][lane] = acc3;
  __syncthreads();

  if (threadIdx.x < B64) {
    const int b = threadIdx.x;
    float z0 = bias[0 * U400 + u] + zs[0][0][b] + zs[0][1][b] + zs[0][2][b] + zs[0][3][b];
    float z1 = bias[1 * U400 + u] + zs[1][0][b] + zs[1][1][b] + zs[1][2][b] + zs[1][3][b];
    float z2 = bias[2 * U400 + u] + zs[2][0][b] + zs[2][1][b] + zs[2][2][b] + zs[2][3][b];
    float z3 = bias[3 * U400 + u] + zs[3][0][b] + zs[3][1][b] + zs[3][2][b] + zs[3][3][b];
    float cp = (t > 0) ? cT[u * B64 + b] : 0.f;
    float ig = 1.f / (1.f + expf(-(z0 + pi[u] * cp)));
    float fg = 1.f / (1.f + expf(-(z1 + pf[u] * cp)));
    float gg = tanhf(z2);
    float cn = fg * cp + ig * gg;
    float og = 1.f / (1.f + expf(-(z3 + po[u] * cn)));
    cT[u * B64 + b] = cn;
    hbuf[((size_t)t * U400 + u) * B64 + b] = og * tanhf(cn);
  }
}

// out[b][t][f] = bd[f] + sum_u h2[t][u][b] * Wd[u][f]
__launch_bounds__(256)
__global__ void dense_k(const float* __restrict__ h2, const float* __restrict__ Wd,
                        const float* __restrict__ bd, float* __restrict__ out) {
  int wid  = blockIdx.x * 4 + (threadIdx.x >> 6);
  int lane = threadIdx.x & 63;
  int t = wid / 3, f = wid - t * 3;
  if (t >= TT) return;
  float acc = bd[f];
  const float* hrow = h2 + (size_t)t * U400 * B64 + lane;
  #pragma unroll 4
  for (int u = 0; u < U400; ++u) acc += hrow[(size_t)u * B64] * Wd[u * 3 + f];
  out[((size_t)lane * TT + t) * 3 + f] = acc;
}

extern "C" void kernel_launch(void* const* d_in, const int* in_sizes, int n_in,
                              void* d_out, int out_size, void* d_ws, size_t ws_size,
                              hipStream_t stream) {
  const float* x   = (const float*)d_in[0];
  const float* Wx0 = (const float*)d_in[1];
  const float* Wh0 = (const float*)d_in[2];
  const float* pi0 = (const float*)d_in[3];
  const float* pf0 = (const float*)d_in[4];
  const float* po0 = (const float*)d_in[5];
  const float* b0  = (const float*)d_in[6];
  const float* Wx1 = (const float*)d_in[7];
  const float* Wh1 = (const float*)d_in[8];
  const float* pi1 = (const float*)d_in[9];
  const float* pf1 = (const float*)d_in[10];
  const float* po1 = (const float*)d_in[11];
  const float* b1  = (const float*)d_in[12];
  const float* Wx2 = (const float*)d_in[13];
  const float* Wh2 = (const float*)d_in[14];
  const float* pi2 = (const float*)d_in[15];
  const float* pf2 = (const float*)d_in[16];
  const float* po2 = (const float*)d_in[17];
  const float* b2  = (const float*)d_in[18];
  const float* Wd  = (const float*)d_in[19];
  const float* bd  = (const float*)d_in[20];

  float* ws   = (float*)d_ws;
  float* xT0  = ws;                  // 98304
  float* WhT0 = xT0  + 98304;        // 640000 each
  float* WhT1 = WhT0 + 640000;
  float* WhT2 = WhT1 + 640000;
  float* WxT1 = WhT2 + 640000;
  float* WxT2 = WxT1 + 640000;
  float* cT   = WxT2 + 640000;       // 25600
  float* hA   = cT   + 25600;        // 13107200 each
  float* hB   = hA   + 13107200;

  hipLaunchKernelGGL(xpose_x_k, dim3(384), dim3(256), 0, stream, x, xT0);

  dim3 tb(32, 8);
  dim3 tg((G1600 + 31) / 32, (U400 + 31) / 32);
  hipLaunchKernelGGL(transpose_k, tg, tb, 0, stream, Wh0, WhT0, U400, G1600);
  hipLaunchKernelGGL(transpose_k, tg, tb, 0, stream, Wh1, WhT1, U400, G1600);
  hipLaunchKernelGGL(transpose_k, tg, tb, 0, stream, Wh2, WhT2, U400, G1600);
  hipLaunchKernelGGL(transpose_k, tg, tb, 0, stream, Wx1, WxT1, U400, G1600);
  hipLaunchKernelGGL(transpose_k, tg, tb, 0, stream, Wx2, WxT2, U400, G1600);

  // layer 0: state in hA
  for (int t = 0; t < TT; ++t)
    hipLaunchKernelGGL(lstm_step_k<1>, dim3(U400), dim3(256), 0, stream,
                       xT0 + (size_t)t * 3 * B64, hA, Wx0, (const float*)nullptr,
                       WhT0, b0, pi0, pf0, po0, cT, t);
  // layer 1: input hA, state hB
  for (int t = 0; t < TT; ++t)
    hipLaunchKernelGGL(lstm_step_k<0>, dim3(U400), dim3(256), 0, stream,
                       hA + (size_t)t * U400 * B64, hB, (const float*)nullptr,
                       WxT1, WhT1, b1, pi1, pf1, po1, cT, t);
  // layer 2: input hB, state hA (layer-0 output no longer needed)
  for (int t = 0; t < TT; ++t)
    hipLaunchKernelGGL(lstm_step_k<0>, dim3(U400), dim3(256), 0, stream,
                       hB + (size_t)t * U400 * B64, hA, (const float*)nullptr,
                       WxT2, WhT2, b2, pi2, pf2, po2, cT, t);

  hipLaunchKernelGGL(dense_k, dim3(384), dim3(256), 0, stream, hA, Wd, bd,
                     (float*)d_out);
}